// Round 3
// baseline (536.140 us; speedup 1.0000x reference)
//
#include <hip/hip_runtime.h>
#include <hip/hip_bf16.h>
#include <math.h>

// Problem constants: B=8, S=1024, D=768, H=12, DH=64. fp32 in, fp32 out.
constexpr int Bn = 8, Sn = 1024, Dn = 768, Hn = 12, DHn = 64;
constexpr int QKV_ELEMS = Bn * Hn * Sn * DHn;  // 6291456

__device__ __forceinline__ float bf2f(unsigned short u) {
    union { unsigned int i; float f; } c; c.i = ((unsigned int)u) << 16; return c.f;
}
__device__ __forceinline__ unsigned short f2bf(float f) {
    __hip_bfloat16 h = __float2bfloat16(f);
    return *reinterpret_cast<unsigned short*>(&h);
}

// ---------------------------------------------------------------------------
// Kernel 1: per-head projections  q/k/v = x_h @ W + b   (fp32 in, bf16 out)
// grid: (B*H)*16 tiles of 64 rows; block 256.
// Outputs laid out [B*H][S][64] bf16 for contiguous per-(b,h) attention reads.
// ---------------------------------------------------------------------------
__global__ __launch_bounds__(256) void proj_kernel(
    const float* __restrict__ x,
    const float* __restrict__ Wq, const float* __restrict__ bq,
    const float* __restrict__ Wk, const float* __restrict__ bk,
    const float* __restrict__ Wv, const float* __restrict__ bv,
    unsigned short* __restrict__ q_ws, unsigned short* __restrict__ k_ws,
    unsigned short* __restrict__ v_ws)
{
    __shared__ float Xs[64][65];   // +1 pad: conflict-free scalar col reads
    __shared__ float Wsf[64 * 64]; // one W matrix at a time, fp32

    const int blk  = blockIdx.x;        // (b*H + h)*16 + tile
    const int tile = blk & 15;
    const int bh   = blk >> 4;
    const int h    = bh % Hn;
    const int b    = bh / Hn;
    const int t    = threadIdx.x;
    const int r    = t >> 2;            // 0..63 row
    const int c0   = (t & 3) * 16;      // 0/16/32/48 col base
    const int s    = tile * 64 + r;

    // stage X tile (64 rows x 64 head-cols)
    {
        const float* xrow = x + ((size_t)(b * Sn + s) * Dn + h * 64 + c0);
        #pragma unroll
        for (int q4 = 0; q4 < 4; q4++) {
            float4 v = ((const float4*)xrow)[q4];
            Xs[r][c0 + 4 * q4 + 0] = v.x;
            Xs[r][c0 + 4 * q4 + 1] = v.y;
            Xs[r][c0 + 4 * q4 + 2] = v.z;
            Xs[r][c0 + 4 * q4 + 3] = v.w;
        }
    }

    const float* Wm[3] = {Wq, Wk, Wv};
    const float* bm[3] = {bq, bk, bv};
    unsigned short* om[3] = {q_ws, k_ws, v_ws};

    for (int m = 0; m < 3; m++) {
        __syncthreads();  // protect Wsf (prev iter readers) and Xs (first iter)
        {   // stage W[h]: 4096 floats, thread t covers [t*16, t*16+16)
            const float* src = Wm[m] + (size_t)h * 4096 + t * 16;
            #pragma unroll
            for (int q4 = 0; q4 < 4; q4++)
                ((float4*)(Wsf + t * 16))[q4] = ((const float4*)src)[q4];
        }
        __syncthreads();

        float acc[16];
        {
            const float* bb = bm[m] + h * 64 + c0;
            #pragma unroll
            for (int j = 0; j < 16; j++) acc[j] = bb[j];
        }

        for (int d = 0; d < 64; d++) {
            float xv = Xs[r][d];
            #pragma unroll
            for (int q4 = 0; q4 < 4; q4++) {
                float4 w = *(const float4*)&Wsf[d * 64 + c0 + 4 * q4];
                acc[4 * q4 + 0] += xv * w.x;
                acc[4 * q4 + 1] += xv * w.y;
                acc[4 * q4 + 2] += xv * w.z;
                acc[4 * q4 + 3] += xv * w.w;
            }
        }

        unsigned short outv[16];
        #pragma unroll
        for (int j = 0; j < 16; j++) outv[j] = f2bf(acc[j]);
        uint4* dst = (uint4*)(om[m] + (size_t)(bh * Sn + s) * 64 + c0);
        dst[0] = ((uint4*)outv)[0];
        dst[1] = ((uint4*)outv)[1];
    }
}

// ---------------------------------------------------------------------------
// Kernel 2: flash attention per (b,h,q-tile of 64). block 256 = 16x16 thread
// grid; thread owns 4 rows x 4 cols of the 64x64 score/output tile.
// Online softmax state (m,l,alpha) in LDS; O accumulator in registers.
// Consumes bf16 workspace; writes fp32 output.
// ---------------------------------------------------------------------------
__global__ __launch_bounds__(256) void attn_kernel(
    const unsigned short* __restrict__ q_ws,
    const unsigned short* __restrict__ k_ws,
    const unsigned short* __restrict__ v_ws,
    float* __restrict__ out)
{
    __shared__ float Qs[64][68];            // fp32, pre-scaled by log2e/sqrt(DH)
    __shared__ unsigned short Ks[64 * 64];  // bf16, 8-elem blocks XOR-swizzled by (row>>2)&7
    __shared__ unsigned short Vs[64 * 64];  // bf16, natural layout
    __shared__ float Ps[64][68];            // scores then probs
    __shared__ float m_s[64], l_s[64], alpha_s[64];
    __shared__ float psum[64][16];

    const int blk = blockIdx.x;   // (b*H+h)*16 + qt
    const int qt  = blk & 15;
    const int bh  = blk >> 4;
    const int t   = threadIdx.x;
    const int tr  = t >> 4;       // row group 0..15 (rows 4tr..4tr+3)
    const int tc  = t & 15;       // col group 0..15 (cols 4tc..4tc+3)
    const int sr  = t >> 2;       // staging row
    const int sc0 = (t & 3) * 16; // staging col base

    const size_t base_bh = (size_t)bh * Sn * 64;

    // load Q tile, pre-scale by 1/sqrt(64) * log2(e) so softmax uses exp2
    {
        constexpr float SC = 0.125f * 1.4426950408889634f;
        const unsigned short* qrow = q_ws + base_bh + (size_t)(qt * 64 + sr) * 64 + sc0;
        uint4 qa = *(const uint4*)qrow;
        uint4 qb = *(const uint4*)(qrow + 8);
        const unsigned short* p0 = (const unsigned short*)&qa;
        const unsigned short* p1 = (const unsigned short*)&qb;
        #pragma unroll
        for (int j = 0; j < 8; j++) Qs[sr][sc0 + j] = bf2f(p0[j]) * SC;
        #pragma unroll
        for (int j = 0; j < 8; j++) Qs[sr][sc0 + 8 + j] = bf2f(p1[j]) * SC;
    }
    if (t < 64) { m_s[t] = -INFINITY; l_s[t] = 0.f; }

    float Oa[4][4];
    #pragma unroll
    for (int i = 0; i < 4; i++)
        #pragma unroll
        for (int j = 0; j < 4; j++) Oa[i][j] = 0.f;

    for (int kt = 0; kt < 16; kt++) {
        __syncthreads();  // protect Ks/Vs from previous-iteration readers
        {   // stage K (swizzled) and V tiles
            const unsigned short* krow = k_ws + base_bh + (size_t)(kt * 64 + sr) * 64 + sc0;
            const unsigned short* vrow = v_ws + base_bh + (size_t)(kt * 64 + sr) * 64 + sc0;
            uint4 ka = *(const uint4*)krow;
            uint4 kb = *(const uint4*)(krow + 8);
            uint4 va = *(const uint4*)vrow;
            uint4 vb = *(const uint4*)(vrow + 8);
            int xr   = (sr >> 2) & 7;
            int blk0 = (sc0 >> 3) ^ xr;
            int blk1 = ((sc0 >> 3) + 1) ^ xr;
            *(uint4*)&Ks[sr * 64 + blk0 * 8] = ka;
            *(uint4*)&Ks[sr * 64 + blk1 * 8] = kb;
            *(uint4*)&Vs[sr * 64 + sc0]      = va;
            *(uint4*)&Vs[sr * 64 + sc0 + 8]  = vb;
        }
        __syncthreads();

        // scores: sreg[i][j] = Q[4tr+i] . K[4tc+j]
        float sreg[4][4];
        #pragma unroll
        for (int i = 0; i < 4; i++)
            #pragma unroll
            for (int j = 0; j < 4; j++) sreg[i][j] = 0.f;

        for (int d0 = 0; d0 < 64; d0 += 8) {
            float kf[4][8];
            #pragma unroll
            for (int j = 0; j < 4; j++) {
                int kr = 4 * tc + j;
                int pb = (d0 >> 3) ^ ((kr >> 2) & 7);
                uint4 kv = *(const uint4*)&Ks[kr * 64 + pb * 8];
                const unsigned short* pk = (const unsigned short*)&kv;
                #pragma unroll
                for (int e = 0; e < 8; e++) kf[j][e] = bf2f(pk[e]);
            }
            #pragma unroll
            for (int i = 0; i < 4; i++) {
                int qr = 4 * tr + i;
                float4 qv0 = *(const float4*)&Qs[qr][d0];
                float4 qv1 = *(const float4*)&Qs[qr][d0 + 4];
                float qf[8] = {qv0.x, qv0.y, qv0.z, qv0.w, qv1.x, qv1.y, qv1.z, qv1.w};
                #pragma unroll
                for (int j = 0; j < 4; j++)
                    #pragma unroll
                    for (int e = 0; e < 8; e++) sreg[i][j] += qf[e] * kf[j][e];
            }
        }

        // publish raw scores for row-max
        #pragma unroll
        for (int i = 0; i < 4; i++)
            *(float4*)&Ps[4 * tr + i][4 * tc] =
                make_float4(sreg[i][0], sreg[i][1], sreg[i][2], sreg[i][3]);
        __syncthreads();

        if (t < 64) {   // per-row online-softmax stats
            float mx = -INFINITY;
            #pragma unroll
            for (int c4 = 0; c4 < 64; c4 += 4) {
                float4 v = *(const float4*)&Ps[t][c4];
                mx = fmaxf(mx, fmaxf(fmaxf(v.x, v.y), fmaxf(v.z, v.w)));
            }
            float mold = m_s[t];
            float mnew = fmaxf(mold, mx);
            float al   = exp2f(mold - mnew);  // 0 on first tile (mold = -inf)
            m_s[t] = mnew; alpha_s[t] = al; l_s[t] *= al;
        }
        __syncthreads();

        // rescale O, exponentiate, publish probs + partial row sums
        #pragma unroll
        for (int i = 0; i < 4; i++) {
            int qr = 4 * tr + i;
            float mi = m_s[qr];
            float al = alpha_s[qr];
            float ps = 0.f;
            #pragma unroll
            for (int j = 0; j < 4; j++) {
                Oa[i][j] *= al;
                float p = exp2f(sreg[i][j] - mi);
                sreg[i][j] = p;
                ps += p;
            }
            *(float4*)&Ps[qr][4 * tc] =
                make_float4(sreg[i][0], sreg[i][1], sreg[i][2], sreg[i][3]);
            psum[qr][tc] = ps;
        }
        __syncthreads();

        if (t < 64) {   // fold partial sums into l
            float s2 = 0.f;
            #pragma unroll
            for (int c = 0; c < 16; c++) s2 += psum[t][c];
            l_s[t] += s2;
        }

        // PV: Oa[i][j] += sum_k P[4tr+i][k] * V[k][4tc+j]
        for (int k0 = 0; k0 < 64; k0 += 4) {
            float pf[4][4];
            #pragma unroll
            for (int i = 0; i < 4; i++) {
                float4 pv = *(const float4*)&Ps[4 * tr + i][k0];
                pf[i][0] = pv.x; pf[i][1] = pv.y; pf[i][2] = pv.z; pf[i][3] = pv.w;
            }
            #pragma unroll
            for (int kk = 0; kk < 4; kk++) {
                uint2 vv = *(const uint2*)&Vs[(k0 + kk) * 64 + 4 * tc];
                const unsigned short* pv = (const unsigned short*)&vv;
                float vf[4] = {bf2f(pv[0]), bf2f(pv[1]), bf2f(pv[2]), bf2f(pv[3])};
                #pragma unroll
                for (int i = 0; i < 4; i++)
                    #pragma unroll
                    for (int j = 0; j < 4; j++) Oa[i][j] += pf[i][kk] * vf[j];
            }
        }
    }
    __syncthreads();

    // epilogue: normalize by l, write fp32 output [B,S,D] with head offset
    const int b = bh / Hn, h = bh % Hn;
    #pragma unroll
    for (int i = 0; i < 4; i++) {
        int qr = 4 * tr + i;
        float inv = 1.0f / l_s[qr];
        int srow = qt * 64 + qr;
        float4 ov = make_float4(Oa[i][0] * inv, Oa[i][1] * inv,
                                Oa[i][2] * inv, Oa[i][3] * inv);
        *(float4*)(out + ((size_t)(b * Sn + srow) * Dn + h * 64 + 4 * tc)) = ov;
    }
}

// ---------------------------------------------------------------------------
extern "C" void kernel_launch(void* const* d_in, const int* in_sizes, int n_in,
                              void* d_out, int out_size, void* d_ws, size_t ws_size,
                              hipStream_t stream) {
    const float* x  = (const float*)d_in[0];
    const float* Wq = (const float*)d_in[1];
    const float* bq = (const float*)d_in[2];
    const float* Wk = (const float*)d_in[3];
    const float* bk = (const float*)d_in[4];
    const float* Wv = (const float*)d_in[5];
    const float* bv = (const float*)d_in[6];
    float* out = (float*)d_out;

    unsigned short* q_ws = (unsigned short*)d_ws;
    unsigned short* k_ws = q_ws + QKV_ELEMS;
    unsigned short* v_ws = k_ws + QKV_ELEMS;

    dim3 grid(Bn * Hn * 16);   // 1536 blocks
    dim3 block(256);
    hipLaunchKernelGGL(proj_kernel, grid, block, 0, stream,
                       x, Wq, bq, Wk, bk, Wv, bv, q_ws, k_ws, v_ws);
    hipLaunchKernelGGL(attn_kernel, grid, block, 0, stream,
                       q_ws, k_ws, v_ws, out);
}

// Round 4
// 315.242 us; speedup vs baseline: 1.7007x; 1.7007x over previous
//
#include <hip/hip_runtime.h>
#include <hip/hip_bf16.h>
#include <math.h>

// Problem constants: B=8, S=1024, D=768, H=12, DH=64. fp32 in, fp32 out.
constexpr int Bn = 8, Sn = 1024, Dn = 768, Hn = 12, DHn = 64;
constexpr int QKV_ELEMS = Bn * Hn * Sn * DHn;  // 6291456

typedef __attribute__((ext_vector_type(8))) short bf16x8;  // 8 bf16 = 4 VGPRs
typedef __attribute__((ext_vector_type(4))) float f32x4;   // MFMA 16x16 C/D

__device__ __forceinline__ float bf2f(unsigned short u) {
    union { unsigned int i; float f; } c; c.i = ((unsigned int)u) << 16; return c.f;
}
__device__ __forceinline__ unsigned short f2bf(float f) {
    __hip_bfloat16 h = __float2bfloat16(f);
    return *reinterpret_cast<unsigned short*>(&h);
}

// ---------------------------------------------------------------------------
// Kernel 1: per-head projections  q/k/v = x_h @ W + b   (fp32 in, bf16 out)
// q_ws,k_ws: [B*H][S][64].  v_ws: TRANSPOSED [B*H][64(dh)][S] so the attention
// kernel's PV B-fragment (V^T rows) is a contiguous b128 LDS read.
// ---------------------------------------------------------------------------
__global__ __launch_bounds__(256) void proj_kernel(
    const float* __restrict__ x,
    const float* __restrict__ Wq, const float* __restrict__ bq,
    const float* __restrict__ Wk, const float* __restrict__ bk,
    const float* __restrict__ Wv, const float* __restrict__ bv,
    unsigned short* __restrict__ q_ws, unsigned short* __restrict__ k_ws,
    unsigned short* __restrict__ v_ws)
{
    __shared__ float Xs[64][65];
    __shared__ float Wsf[64 * 64];

    const int blk  = blockIdx.x;        // (b*H + h)*16 + tile
    const int tile = blk & 15;
    const int bh   = blk >> 4;
    const int h    = bh % Hn;
    const int b    = bh / Hn;
    const int t    = threadIdx.x;
    const int r    = t >> 2;            // 0..63 row (seq within tile)
    const int c0   = (t & 3) * 16;      // col base
    const int s    = tile * 64 + r;     // seq index 0..1023

    {
        const float* xrow = x + ((size_t)(b * Sn + s) * Dn + h * 64 + c0);
        #pragma unroll
        for (int q4 = 0; q4 < 4; q4++) {
            float4 v = ((const float4*)xrow)[q4];
            Xs[r][c0 + 4 * q4 + 0] = v.x;
            Xs[r][c0 + 4 * q4 + 1] = v.y;
            Xs[r][c0 + 4 * q4 + 2] = v.z;
            Xs[r][c0 + 4 * q4 + 3] = v.w;
        }
    }

    const float* Wm[3] = {Wq, Wk, Wv};
    const float* bm[3] = {bq, bk, bv};

    for (int m = 0; m < 3; m++) {
        __syncthreads();
        {
            const float* src = Wm[m] + (size_t)h * 4096 + t * 16;
            #pragma unroll
            for (int q4 = 0; q4 < 4; q4++)
                ((float4*)(Wsf + t * 16))[q4] = ((const float4*)src)[q4];
        }
        __syncthreads();

        float acc[16];
        {
            const float* bb = bm[m] + h * 64 + c0;
            #pragma unroll
            for (int j = 0; j < 16; j++) acc[j] = bb[j];
        }
        for (int d = 0; d < 64; d++) {
            float xv = Xs[r][d];
            #pragma unroll
            for (int q4 = 0; q4 < 4; q4++) {
                float4 w = *(const float4*)&Wsf[d * 64 + c0 + 4 * q4];
                acc[4 * q4 + 0] += xv * w.x;
                acc[4 * q4 + 1] += xv * w.y;
                acc[4 * q4 + 2] += xv * w.z;
                acc[4 * q4 + 3] += xv * w.w;
            }
        }

        if (m == 2) {   // V: write transposed [bh][dh][seq]
            unsigned short* vt = v_ws + (size_t)bh * 64 * Sn;
            #pragma unroll
            for (int j = 0; j < 16; j++)
                vt[(size_t)(c0 + j) * Sn + s] = f2bf(acc[j]);
        } else {
            unsigned short outv[16];
            #pragma unroll
            for (int j = 0; j < 16; j++) outv[j] = f2bf(acc[j]);
            unsigned short* o = (m == 0 ? q_ws : k_ws);
            uint4* dst = (uint4*)(o + (size_t)(bh * Sn + s) * 64 + c0);
            dst[0] = ((uint4*)outv)[0];
            dst[1] = ((uint4*)outv)[1];
        }
    }
}

// ---------------------------------------------------------------------------
// Kernel 2: MFMA flash attention. Block = 4 waves; wave w owns Q-strip rows
// [qt*64 + w*16, +16). Per k-tile: QK^T via 8 mfma_16x16x32_bf16, in-register
// shuffle softmax (16-lane quad groups), P->LDS (C-layout -> A-layout), PV via
// 8 MFMAs reading V^T rows. LDS rows padded to 72 bf16 (144B: 16B-aligned,
// 2-way banks = free).
// ---------------------------------------------------------------------------
__global__ __launch_bounds__(256) void attn_kernel(
    const unsigned short* __restrict__ q_ws,
    const unsigned short* __restrict__ k_ws,
    const unsigned short* __restrict__ vt_ws,
    float* __restrict__ out)
{
    __shared__ unsigned short Ks[64 * 72];      // [key][dh] padded
    __shared__ unsigned short Vt[64 * 72];      // [dh][key] padded
    __shared__ unsigned short Pws[4 * 16 * 72]; // per-wave P strip [row][key]

    const int blk  = blockIdx.x;   // (b*H+h)*16 + qt
    const int qt   = blk & 15;
    const int bh   = blk >> 4;
    const int t    = threadIdx.x;
    const int w    = t >> 6;        // wave 0..3
    const int lane = t & 63;
    const int l    = lane & 15;     // fragment free-dim index
    const int quad = lane >> 4;     // 0..3
    const int sr   = t >> 2;        // staging row 0..63
    const int sc0  = (t & 3) * 16;  // staging col base

    const size_t base  = (size_t)bh * Sn * 64;   // q/k [bh][s][64]
    const size_t vbase = (size_t)bh * 64 * Sn;   // vt  [bh][dh][S]
    constexpr float C = 0.125f * 1.4426950408889634f;  // log2(e)/sqrt(64)

    // Q A-fragments, straight from global (A[m=l][k=quad*8+j], 2 k-chunks)
    bf16x8 qf[2];
    {
        const unsigned short* qp = q_ws + base + (size_t)(qt * 64 + w * 16 + l) * 64 + quad * 8;
        uint4 a = *(const uint4*)qp;
        uint4 b = *(const uint4*)(qp + 32);
        qf[0] = *(bf16x8*)&a;
        qf[1] = *(bf16x8*)&b;
    }

    float m_st[4], l_st[4];
    #pragma unroll
    for (int r = 0; r < 4; r++) { m_st[r] = -INFINITY; l_st[r] = 0.f; }
    f32x4 Oa[4];
    #pragma unroll
    for (int nt = 0; nt < 4; nt++) Oa[nt] = (f32x4){0.f, 0.f, 0.f, 0.f};

    unsigned short* Pw = Pws + w * 16 * 72;

    for (int kt = 0; kt < 16; kt++) {
        __syncthreads();  // drain prev-iter LDS readers
        {   // stage K tile [key][dh] and V^T tile [dh][key]
            const unsigned short* kp = k_ws + base + (size_t)(kt * 64 + sr) * 64 + sc0;
            uint4 ka = *(const uint4*)kp;
            uint4 kb = *(const uint4*)(kp + 8);
            const unsigned short* vp = vt_ws + vbase + (size_t)sr * Sn + kt * 64 + sc0;
            uint4 va = *(const uint4*)vp;
            uint4 vb = *(const uint4*)(vp + 8);
            *(uint4*)&Ks[sr * 72 + sc0]     = ka;
            *(uint4*)&Ks[sr * 72 + sc0 + 8] = kb;
            *(uint4*)&Vt[sr * 72 + sc0]     = va;
            *(uint4*)&Vt[sr * 72 + sc0 + 8] = vb;
        }
        __syncthreads();

        // QK^T: s[nt] = Q_strip(16x64) . K^T(:, nt*16..+16)
        f32x4 s[4];
        #pragma unroll
        for (int nt = 0; nt < 4; nt++) s[nt] = (f32x4){0.f, 0.f, 0.f, 0.f};
        #pragma unroll
        for (int nt = 0; nt < 4; nt++)
            #pragma unroll
            for (int kc = 0; kc < 2; kc++) {
                bf16x8 kf = *(bf16x8*)&Ks[(nt * 16 + l) * 72 + kc * 32 + quad * 8];
                s[nt] = __builtin_amdgcn_mfma_f32_16x16x32_bf16(qf[kc], kf, s[nt], 0, 0, 0);
            }

        // row max over 64 cols: per-lane over nt, then shuffle across quad's 16 lanes
        float mx[4];
        #pragma unroll
        for (int r = 0; r < 4; r++)
            mx[r] = fmaxf(fmaxf(s[0][r], s[1][r]), fmaxf(s[2][r], s[3][r]));
        #pragma unroll
        for (int d = 1; d < 16; d <<= 1)
            #pragma unroll
            for (int r = 0; r < 4; r++)
                mx[r] = fmaxf(mx[r], __shfl_xor(mx[r], d, 64));

        float alpha[4], cm[4];
        #pragma unroll
        for (int r = 0; r < 4; r++) {
            float mn = fmaxf(m_st[r], mx[r]);
            alpha[r] = exp2f(C * (m_st[r] - mn));   // 0 on first tile
            m_st[r]  = mn;
            cm[r]    = C * mn;
        }

        // p = exp2(C*s - C*m); partial row sums
        float ps[4] = {0.f, 0.f, 0.f, 0.f};
        #pragma unroll
        for (int nt = 0; nt < 4; nt++)
            #pragma unroll
            for (int r = 0; r < 4; r++) {
                float p = exp2f(fmaf(C, s[nt][r], -cm[r]));
                s[nt][r] = p;
                ps[r] += p;
            }
        #pragma unroll
        for (int d = 1; d < 16; d <<= 1)
            #pragma unroll
            for (int r = 0; r < 4; r++)
                ps[r] += __shfl_xor(ps[r], d, 64);
        #pragma unroll
        for (int r = 0; r < 4; r++) l_st[r] = l_st[r] * alpha[r] + ps[r];

        // rescale O
        #pragma unroll
        for (int nt = 0; nt < 4; nt++)
            #pragma unroll
            for (int r = 0; r < 4; r++) Oa[nt][r] *= alpha[r];

        // P (C-layout) -> LDS -> A-layout fragments
        #pragma unroll
        for (int nt = 0; nt < 4; nt++)
            #pragma unroll
            for (int r = 0; r < 4; r++)
                Pw[(quad * 4 + r) * 72 + nt * 16 + l] = f2bf(s[nt][r]);
        __asm__ volatile("s_waitcnt lgkmcnt(0)" ::: "memory");

        bf16x8 pf[2];
        pf[0] = *(bf16x8*)&Pw[l * 72 + quad * 8];
        pf[1] = *(bf16x8*)&Pw[l * 72 + 32 + quad * 8];

        // PV: Oa[nt] += P(16x64) . V(:, nt*16..+16)  via V^T rows
        #pragma unroll
        for (int nt = 0; nt < 4; nt++)
            #pragma unroll
            for (int kc = 0; kc < 2; kc++) {
                bf16x8 vf = *(bf16x8*)&Vt[(nt * 16 + l) * 72 + kc * 32 + quad * 8];
                Oa[nt] = __builtin_amdgcn_mfma_f32_16x16x32_bf16(pf[kc], vf, Oa[nt], 0, 0, 0);
            }
    }

    // epilogue: normalize, write fp32 [B,S,D]
    const int b = bh / Hn, h = bh % Hn;
    float inv[4];
    #pragma unroll
    for (int r = 0; r < 4; r++) inv[r] = 1.0f / l_st[r];
    #pragma unroll
    for (int nt = 0; nt < 4; nt++)
        #pragma unroll
        for (int r = 0; r < 4; r++) {
            int srow = qt * 64 + w * 16 + quad * 4 + r;
            out[(size_t)(b * Sn + srow) * Dn + h * 64 + nt * 16 + l] = Oa[nt][r] * inv[r];
        }
}

// ---------------------------------------------------------------------------
extern "C" void kernel_launch(void* const* d_in, const int* in_sizes, int n_in,
                              void* d_out, int out_size, void* d_ws, size_t ws_size,
                              hipStream_t stream) {
    const float* x  = (const float*)d_in[0];
    const float* Wq = (const float*)d_in[1];
    const float* bq = (const float*)d_in[2];
    const float* Wk = (const float*)d_in[3];
    const float* bk = (const float*)d_in[4];
    const float* Wv = (const float*)d_in[5];
    const float* bv = (const float*)d_in[6];
    float* out = (float*)d_out;

    unsigned short* q_ws  = (unsigned short*)d_ws;
    unsigned short* k_ws  = q_ws + QKV_ELEMS;
    unsigned short* vt_ws = k_ws + QKV_ELEMS;

    dim3 grid(Bn * Hn * 16);   // 1536 blocks
    dim3 block(256);
    hipLaunchKernelGGL(proj_kernel, grid, block, 0, stream,
                       x, Wq, bq, Wk, bk, Wv, bv, q_ws, k_ws, vt_ws);
    hipLaunchKernelGGL(attn_kernel, grid, block, 0, stream,
                       q_ws, k_ws, vt_ws, out);
}

// Round 5
// 188.232 us; speedup vs baseline: 2.8483x; 1.6748x over previous
//
#include <hip/hip_runtime.h>
#include <hip/hip_bf16.h>
#include <math.h>

// Problem constants: B=8, S=1024, D=768, H=12, DH=64. fp32 in, fp32 out.
constexpr int Bn = 8, Sn = 1024, Dn = 768, Hn = 12, DHn = 64;
constexpr int QKV_ELEMS = Bn * Hn * Sn * DHn;  // 6291456

typedef __attribute__((ext_vector_type(8))) short bf16x8;  // 8 bf16 = 4 VGPRs
typedef __attribute__((ext_vector_type(4))) float f32x4;   // MFMA 16x16 C/D

__device__ __forceinline__ float bf2f(unsigned short u) {
    union { unsigned int i; float f; } c; c.i = ((unsigned int)u) << 16; return c.f;
}
__device__ __forceinline__ unsigned short f2bf(float f) {
    __hip_bfloat16 h = __float2bfloat16(f);
    return *reinterpret_cast<unsigned short*>(&h);
}

// ---------------------------------------------------------------------------
// Kernel 1: MFMA projections. Block = 256 thr / 4 waves, one 64-seq tile.
// Stage X (bf16) + all three W^T (bf16) in LDS once, then 24 MFMAs per wave:
//   q,k : D[m=s][n=e] = X(16x64) . (W^T rows as B)     -> q_ws/k_ws [bh][s][64]
//   v   : D[m=e][n=s] = W^T_v(16x64) . (X rows as B)   -> vt_ws [bh][dh][S]
// (V computed directly transposed so attention PV B-frags are contiguous.)
// LDS rows padded to 72 bf16 (144 B) — 2-way banks only (free).
// ---------------------------------------------------------------------------
__global__ __launch_bounds__(256) void proj_kernel(
    const float* __restrict__ x,
    const float* __restrict__ Wq, const float* __restrict__ bq,
    const float* __restrict__ Wk, const float* __restrict__ bk,
    const float* __restrict__ Wv, const float* __restrict__ bv,
    unsigned short* __restrict__ q_ws, unsigned short* __restrict__ k_ws,
    unsigned short* __restrict__ vt_ws)
{
    __shared__ unsigned short Xs[64 * 72];      // [s][d] bf16
    __shared__ unsigned short Wt[3][64 * 72];   // [e][d] bf16 (transposed)

    const int blk  = blockIdx.x;        // (b*H + h)*16 + tile
    const int tile = blk & 15;
    const int bh   = blk >> 4;
    const int h    = bh % Hn;
    const int b    = bh / Hn;
    const int t    = threadIdx.x;
    const int w    = t >> 6;            // wave 0..3
    const int lane = t & 63;
    const int l    = lane & 15;
    const int quad = lane >> 4;
    const int r    = t >> 2;            // staging row 0..63
    const int c0   = (t & 3) * 16;      // staging col base
    const int s0   = tile * 64;

    // ---- stage X tile [64 s][64 d] fp32 -> bf16 LDS ----
    {
        const float* xrow = x + ((size_t)(b * Sn + s0 + r) * Dn + h * 64 + c0);
        unsigned short tmp[16];
        #pragma unroll
        for (int q4 = 0; q4 < 4; q4++) {
            float4 v = ((const float4*)xrow)[q4];
            tmp[4 * q4 + 0] = f2bf(v.x);
            tmp[4 * q4 + 1] = f2bf(v.y);
            tmp[4 * q4 + 2] = f2bf(v.z);
            tmp[4 * q4 + 3] = f2bf(v.w);
        }
        *(uint4*)&Xs[r * 72 + c0]     = ((uint4*)tmp)[0];
        *(uint4*)&Xs[r * 72 + c0 + 8] = ((uint4*)tmp)[1];
    }

    // ---- stage W^T for q,k,v: thread t reads W[h] row d=r, cols c0..c0+15 ----
    const float* Wm[3] = {Wq, Wk, Wv};
    #pragma unroll
    for (int m = 0; m < 3; m++) {
        const float* src = Wm[m] + (size_t)h * 4096 + r * 64 + c0;
        #pragma unroll
        for (int q4 = 0; q4 < 4; q4++) {
            float4 v = ((const float4*)src)[q4];
            Wt[m][(c0 + 4 * q4 + 0) * 72 + r] = f2bf(v.x);
            Wt[m][(c0 + 4 * q4 + 1) * 72 + r] = f2bf(v.y);
            Wt[m][(c0 + 4 * q4 + 2) * 72 + r] = f2bf(v.z);
            Wt[m][(c0 + 4 * q4 + 3) * 72 + r] = f2bf(v.w);
        }
    }
    __syncthreads();

    // ---- per-wave X A-fragments (rows w*16+l) ----
    bf16x8 xa[2];
    xa[0] = *(bf16x8*)&Xs[(w * 16 + l) * 72 + quad * 8];
    xa[1] = *(bf16x8*)&Xs[(w * 16 + l) * 72 + 32 + quad * 8];

    // ---- q and k: D[m = s-row (quad*4+rr)][n = e (nt*16+l)] ----
    #pragma unroll
    for (int m = 0; m < 2; m++) {
        const float* bias = (m == 0 ? bq : bk) + h * 64;
        unsigned short* o = (m == 0 ? q_ws : k_ws);
        f32x4 acc[4];
        #pragma unroll
        for (int nt = 0; nt < 4; nt++) {
            float bv_ = bias[nt * 16 + l];
            acc[nt] = (f32x4){bv_, bv_, bv_, bv_};
        }
        #pragma unroll
        for (int nt = 0; nt < 4; nt++)
            #pragma unroll
            for (int kc = 0; kc < 2; kc++) {
                bf16x8 wb = *(bf16x8*)&Wt[m][(nt * 16 + l) * 72 + kc * 32 + quad * 8];
                acc[nt] = __builtin_amdgcn_mfma_f32_16x16x32_bf16(xa[kc], wb, acc[nt], 0, 0, 0);
            }
        #pragma unroll
        for (int nt = 0; nt < 4; nt++)
            #pragma unroll
            for (int rr = 0; rr < 4; rr++) {
                int srow = s0 + w * 16 + quad * 4 + rr;
                o[(size_t)(bh * Sn + srow) * 64 + nt * 16 + l] = f2bf(acc[nt][rr]);
            }
    }

    // ---- v transposed: D[m = e (quad*4+rr within e-strip w)][n = s (nt*16+l)] ----
    {
        bf16x8 wva[2];
        wva[0] = *(bf16x8*)&Wt[2][(w * 16 + l) * 72 + quad * 8];
        wva[1] = *(bf16x8*)&Wt[2][(w * 16 + l) * 72 + 32 + quad * 8];
        f32x4 acc[4];
        float bvr[4];
        #pragma unroll
        for (int rr = 0; rr < 4; rr++) bvr[rr] = bv[h * 64 + w * 16 + quad * 4 + rr];
        #pragma unroll
        for (int nt = 0; nt < 4; nt++)
            acc[nt] = (f32x4){bvr[0], bvr[1], bvr[2], bvr[3]};
        #pragma unroll
        for (int nt = 0; nt < 4; nt++)
            #pragma unroll
            for (int kc = 0; kc < 2; kc++) {
                bf16x8 xb = *(bf16x8*)&Xs[(nt * 16 + l) * 72 + kc * 32 + quad * 8];
                acc[nt] = __builtin_amdgcn_mfma_f32_16x16x32_bf16(wva[kc], xb, acc[nt], 0, 0, 0);
            }
        unsigned short* vt = vt_ws + (size_t)bh * 64 * Sn;
        #pragma unroll
        for (int nt = 0; nt < 4; nt++)
            #pragma unroll
            for (int rr = 0; rr < 4; rr++) {
                int e = w * 16 + quad * 4 + rr;
                vt[(size_t)e * Sn + s0 + nt * 16 + l] = f2bf(acc[nt][rr]);
            }
    }
}

// ---------------------------------------------------------------------------
// Kernel 2: MFMA flash attention (unchanged from round 4 — passed, ~160 us).
// ---------------------------------------------------------------------------
__global__ __launch_bounds__(256) void attn_kernel(
    const unsigned short* __restrict__ q_ws,
    const unsigned short* __restrict__ k_ws,
    const unsigned short* __restrict__ vt_ws,
    float* __restrict__ out)
{
    __shared__ unsigned short Ks[64 * 72];      // [key][dh] padded
    __shared__ unsigned short Vt[64 * 72];      // [dh][key] padded
    __shared__ unsigned short Pws[4 * 16 * 72]; // per-wave P strip [row][key]

    const int blk  = blockIdx.x;   // (b*H+h)*16 + qt
    const int qt   = blk & 15;
    const int bh   = blk >> 4;
    const int t    = threadIdx.x;
    const int w    = t >> 6;
    const int lane = t & 63;
    const int l    = lane & 15;
    const int quad = lane >> 4;
    const int sr   = t >> 2;
    const int sc0  = (t & 3) * 16;

    const size_t base  = (size_t)bh * Sn * 64;
    const size_t vbase = (size_t)bh * 64 * Sn;
    constexpr float C = 0.125f * 1.4426950408889634f;  // log2(e)/sqrt(64)

    bf16x8 qf[2];
    {
        const unsigned short* qp = q_ws + base + (size_t)(qt * 64 + w * 16 + l) * 64 + quad * 8;
        uint4 a = *(const uint4*)qp;
        uint4 b = *(const uint4*)(qp + 32);
        qf[0] = *(bf16x8*)&a;
        qf[1] = *(bf16x8*)&b;
    }

    float m_st[4], l_st[4];
    #pragma unroll
    for (int r = 0; r < 4; r++) { m_st[r] = -INFINITY; l_st[r] = 0.f; }
    f32x4 Oa[4];
    #pragma unroll
    for (int nt = 0; nt < 4; nt++) Oa[nt] = (f32x4){0.f, 0.f, 0.f, 0.f};

    unsigned short* Pw = Pws + w * 16 * 72;

    for (int kt = 0; kt < 16; kt++) {
        __syncthreads();
        {
            const unsigned short* kp = k_ws + base + (size_t)(kt * 64 + sr) * 64 + sc0;
            uint4 ka = *(const uint4*)kp;
            uint4 kb = *(const uint4*)(kp + 8);
            const unsigned short* vp = vt_ws + vbase + (size_t)sr * Sn + kt * 64 + sc0;
            uint4 va = *(const uint4*)vp;
            uint4 vb = *(const uint4*)(vp + 8);
            *(uint4*)&Ks[sr * 72 + sc0]     = ka;
            *(uint4*)&Ks[sr * 72 + sc0 + 8] = kb;
            *(uint4*)&Vt[sr * 72 + sc0]     = va;
            *(uint4*)&Vt[sr * 72 + sc0 + 8] = vb;
        }
        __syncthreads();

        f32x4 s[4];
        #pragma unroll
        for (int nt = 0; nt < 4; nt++) s[nt] = (f32x4){0.f, 0.f, 0.f, 0.f};
        #pragma unroll
        for (int nt = 0; nt < 4; nt++)
            #pragma unroll
            for (int kc = 0; kc < 2; kc++) {
                bf16x8 kf = *(bf16x8*)&Ks[(nt * 16 + l) * 72 + kc * 32 + quad * 8];
                s[nt] = __builtin_amdgcn_mfma_f32_16x16x32_bf16(qf[kc], kf, s[nt], 0, 0, 0);
            }

        float mx[4];
        #pragma unroll
        for (int r = 0; r < 4; r++)
            mx[r] = fmaxf(fmaxf(s[0][r], s[1][r]), fmaxf(s[2][r], s[3][r]));
        #pragma unroll
        for (int d = 1; d < 16; d <<= 1)
            #pragma unroll
            for (int r = 0; r < 4; r++)
                mx[r] = fmaxf(mx[r], __shfl_xor(mx[r], d, 64));

        float alpha[4], cm[4];
        #pragma unroll
        for (int r = 0; r < 4; r++) {
            float mn = fmaxf(m_st[r], mx[r]);
            alpha[r] = exp2f(C * (m_st[r] - mn));
            m_st[r]  = mn;
            cm[r]    = C * mn;
        }

        float ps[4] = {0.f, 0.f, 0.f, 0.f};
        #pragma unroll
        for (int nt = 0; nt < 4; nt++)
            #pragma unroll
            for (int r = 0; r < 4; r++) {
                float p = exp2f(fmaf(C, s[nt][r], -cm[r]));
                s[nt][r] = p;
                ps[r] += p;
            }
        #pragma unroll
        for (int d = 1; d < 16; d <<= 1)
            #pragma unroll
            for (int r = 0; r < 4; r++)
                ps[r] += __shfl_xor(ps[r], d, 64);
        #pragma unroll
        for (int r = 0; r < 4; r++) l_st[r] = l_st[r] * alpha[r] + ps[r];

        #pragma unroll
        for (int nt = 0; nt < 4; nt++)
            #pragma unroll
            for (int r = 0; r < 4; r++) Oa[nt][r] *= alpha[r];

        #pragma unroll
        for (int nt = 0; nt < 4; nt++)
            #pragma unroll
            for (int r = 0; r < 4; r++)
                Pw[(quad * 4 + r) * 72 + nt * 16 + l] = f2bf(s[nt][r]);
        __asm__ volatile("s_waitcnt lgkmcnt(0)" ::: "memory");

        bf16x8 pf[2];
        pf[0] = *(bf16x8*)&Pw[l * 72 + quad * 8];
        pf[1] = *(bf16x8*)&Pw[l * 72 + 32 + quad * 8];

        #pragma unroll
        for (int nt = 0; nt < 4; nt++)
            #pragma unroll
            for (int kc = 0; kc < 2; kc++) {
                bf16x8 vf = *(bf16x8*)&Vt[(nt * 16 + l) * 72 + kc * 32 + quad * 8];
                Oa[nt] = __builtin_amdgcn_mfma_f32_16x16x32_bf16(pf[kc], vf, Oa[nt], 0, 0, 0);
            }
    }

    const int b = bh / Hn, h = bh % Hn;
    float inv[4];
    #pragma unroll
    for (int r = 0; r < 4; r++) inv[r] = 1.0f / l_st[r];
    #pragma unroll
    for (int nt = 0; nt < 4; nt++)
        #pragma unroll
        for (int r = 0; r < 4; r++) {
            int srow = qt * 64 + w * 16 + quad * 4 + r;
            out[(size_t)(b * Sn + srow) * Dn + h * 64 + nt * 16 + l] = Oa[nt][r] * inv[r];
        }
}

// ---------------------------------------------------------------------------
extern "C" void kernel_launch(void* const* d_in, const int* in_sizes, int n_in,
                              void* d_out, int out_size, void* d_ws, size_t ws_size,
                              hipStream_t stream) {
    const float* x  = (const float*)d_in[0];
    const float* Wq = (const float*)d_in[1];
    const float* bq = (const float*)d_in[2];
    const float* Wk = (const float*)d_in[3];
    const float* bk = (const float*)d_in[4];
    const float* Wv = (const float*)d_in[5];
    const float* bv = (const float*)d_in[6];
    float* out = (float*)d_out;

    unsigned short* q_ws  = (unsigned short*)d_ws;
    unsigned short* k_ws  = q_ws + QKV_ELEMS;
    unsigned short* vt_ws = k_ws + QKV_ELEMS;

    dim3 grid(Bn * Hn * 16);   // 1536 blocks
    dim3 block(256);
    hipLaunchKernelGGL(proj_kernel, grid, block, 0, stream,
                       x, Wq, bq, Wk, bk, Wv, bv, q_ws, k_ws, vt_ws);
    hipLaunchKernelGGL(attn_kernel, grid, block, 0, stream,
                       q_ws, k_ws, vt_ws, out);
}